// Round 8
// baseline (386.135 us; speedup 1.0000x reference)
//
#include <hip/hip_runtime.h>

typedef __bf16 bf16;
typedef __bf16 bf16x2 __attribute__((ext_vector_type(2)));
typedef __bf16 bf16x8 __attribute__((ext_vector_type(8)));
typedef __bf16 bf16x4 __attribute__((ext_vector_type(4)));
typedef float  f32x4  __attribute__((ext_vector_type(4)));
typedef float  f32x16 __attribute__((ext_vector_type(16)));
typedef unsigned int uint;

// ---------------------------------------------------------------- helpers
static __device__ __forceinline__ void async_copy16(const void* g, void* l) {
  __builtin_amdgcn_global_load_lds((__attribute__((address_space(1))) void*)g,
                                   (__attribute__((address_space(3))) void*)l,
                                   16, 0, 0);
}

static __device__ __forceinline__ uint pkbf2(float a, float b) {
  union { bf16x2 v; uint u; } x;
  x.v[0] = (bf16)a; x.v[1] = (bf16)b;
  return x.u;
}

union U4 { uint u[4]; bf16x8 v; };

// ---------------------------------------------------------------- fp32 -> bf16 all four weights, one launch
__global__ __launch_bounds__(256)
void f2b_all(const float* __restrict__ s0, const float* __restrict__ s1,
             const float* __restrict__ s2, const float* __restrict__ s3,
             bf16* __restrict__ d0, bf16* __restrict__ d1,
             bf16* __restrict__ d2, bf16* __restrict__ d3) {
  int i = blockIdx.x * 256 + threadIdx.x;   // float4 units, total 3145728
  const float* s; bf16* d; int j;
  if (i < 786432)       { s = s0; d = d0; j = i; }
  else if (i < 1048576) { s = s1; d = d1; j = i - 786432; }
  else if (i < 2097152) { s = s2; d = d2; j = i - 1048576; }
  else                  { s = s3; d = d3; j = i - 2097152; }
  float4 v = ((const float4*)s)[j];
  bf16x4 o;
  o[0] = (bf16)v.x; o[1] = (bf16)v.y; o[2] = (bf16)v.z; o[3] = (bf16)v.w;
  ((bf16x4*)d)[j] = o;
}

// ---------------------------------------------------------------- (a[+b]) -> residual fp32 + rmsnorm bf16
__global__ __launch_bounds__(256)
void add_rmsnorm_kernel(const float* __restrict__ a, const float* __restrict__ b,
                        const float* __restrict__ g, float* __restrict__ xout,
                        bf16* __restrict__ hout) {
  const int row = blockIdx.x;
  const int tid = threadIdx.x;
  const size_t base = (size_t)row * 1024 + tid * 4;
  float4 x = *(const float4*)(a + base);
  if (b) {
    float4 y = *(const float4*)(b + base);
    x.x += y.x; x.y += y.y; x.z += y.z; x.w += y.w;
  }
  float ss = x.x*x.x + x.y*x.y + x.z*x.z + x.w*x.w;
#pragma unroll
  for (int off = 32; off > 0; off >>= 1) ss += __shfl_xor(ss, off, 64);
  __shared__ float red[4];
  const int wave = tid >> 6, lane = tid & 63;
  if (lane == 0) red[wave] = ss;
  __syncthreads();
  const float total = red[0] + red[1] + red[2] + red[3];
  const float scale = rsqrtf(total * (1.0f / 1024.0f) + 1e-6f);
  if (xout) *(float4*)(xout + base) = x;
  float4 gv = *(const float4*)(g + tid * 4);
  bf16x4 h;
  h[0] = (bf16)(x.x * scale * gv.x);
  h[1] = (bf16)(x.y * scale * gv.y);
  h[2] = (bf16)(x.z * scale * gv.z);
  h[3] = (bf16)(x.w * scale * gv.w);
  *(bf16x4*)(hout + base) = h;
}

// ---------------------------------------------------------------- GEMM 128x128, BK=64
// Epilogues route the C-tile through the (dead) staging LDS, re-padded to
// 128x136 bf16 (row stride rotates banks by 4 -> conflict-free b128 reads),
// then store coalesced 32 B/lane. EP_QKV: RoPE fused in-register; q
// pre-scaled for exp2 softmax; V^T kv-permutation folded into the LDS write.
enum { EP_QKV = 0, EP_SILU = 2 };

template <int MODE>
__global__ __launch_bounds__(256)
void gemm_bt(const bf16* __restrict__ A, const bf16* __restrict__ W,
             bf16* __restrict__ outB, bf16* __restrict__ outB2,
             int M, int N, int K) {
  __shared__ bf16 sh[17408];               // 34816 B; staging uses first 32 KB
  bf16* As = sh;                           // [128][64]
  bf16* Bs = sh + 8192;                    // [128][64]
  const int tid  = threadIdx.x;
  const int wave = tid >> 6;
  const int lane = tid & 63;
  const int quad = lane >> 4;
  const int l16  = lane & 15;

  const int bm = blockIdx.x & 31;          // M/128 == 32 always here
  const int bn = blockIdx.x >> 5;
  const int m0 = bm << 7, n0 = bn << 7;
  const int wm = (wave >> 1) << 6;
  const int wn = (wave & 1) << 6;

  const int rl = lane >> 3;
  const int cg = (lane & 7) ^ rl;
  const bf16* gA = A + (size_t)(m0 + wave * 32 + rl) * K + cg * 8;
  const bf16* gB = W + (size_t)(n0 + wave * 32 + rl) * K + cg * 8;

  const int s8 = l16 & 7;
  f32x4 acc[4][4] = {};

  for (int k0 = 0; k0 < K; k0 += 64) {
    __syncthreads();
#pragma unroll
    for (int i = 0; i < 4; i++) {
      async_copy16(gA + (size_t)(i * 8) * K, &As[(wave * 32 + i * 8) * 64]);
      async_copy16(gB + (size_t)(i * 8) * K, &Bs[(wave * 32 + i * 8) * 64]);
    }
    gA += 64; gB += 64;
    __syncthreads();
#pragma unroll
    for (int kh = 0; kh < 2; kh++) {
      bf16x8 af[4], bfr[4];
#pragma unroll
      for (int i = 0; i < 4; i++)
        af[i] = *(const bf16x8*)&As[(wm + i * 16 + l16) * 64 + (((kh * 4 + quad) ^ s8) * 8)];
#pragma unroll
      for (int j = 0; j < 4; j++)
        bfr[j] = *(const bf16x8*)&Bs[(wn + j * 16 + l16) * 64 + (((kh * 4 + quad) ^ s8) * 8)];
#pragma unroll
      for (int i = 0; i < 4; i++)
#pragma unroll
        for (int j = 0; j < 4; j++)
          acc[i][j] = __builtin_amdgcn_mfma_f32_16x16x32_bf16(af[i], bfr[j], acc[i][j], 0, 0, 0);
    }
  }

  __syncthreads();                         // staging dead; reuse as Ct[128][136]
  const int bb = m0 >> 11;                 // batch (tile never crosses 2048)
  const int l0 = m0 & 2047;

  if constexpr (MODE == EP_QKV) {
    const int which = n0 >> 10;            // block-uniform (0=q,1=k,2=v)
    if (which == 2) {
      // Ct[n_loc][lp(m_loc)] = V  (kv perm: swap bits 2,3)
#pragma unroll
      for (int i = 0; i < 4; i++) {
#pragma unroll
        for (int j = 0; j < 4; j++) {
          const int n_loc = wn + j * 16 + l16;
#pragma unroll
          for (int r = 0; r < 4; r++) {
            const int m = wm + i * 16 + quad * 4 + r;
            const int lp = (m & ~15) | (m & 3) | ((m & 4) << 1) | ((m & 8) >> 1);
            sh[n_loc * 136 + lp] = (bf16)acc[i][j][r];
          }
        }
      }
      __syncthreads();
      // rows = d (2 heads), cols = l contiguous 256 B
#pragma unroll
      for (int p = 0; p < 4; p++) {
        const int row = p * 32 + (tid >> 3);
        const int col = (tid & 7) * 16;
        const int n = n0 + row;
        const int hh = (n >> 6) & 15, hd = n & 63;
        bf16* dst = outB2 + ((size_t)(bb * 16 + hh) * 64 + hd) * 2048 + l0 + col;
        const uint4* src = (const uint4*)&sh[row * 136 + col];
        *(uint4*)dst = src[0];
        *(uint4*)(dst + 8) = src[1];
      }
    } else {
      const float sc = (which == 0) ? 0.1803368801111243f : 1.0f;
#pragma unroll
      for (int jp = 0; jp < 2; jp++) {     // pair (jp, jp+2): hd1, hd1+32
        const int n_loc = wn + jp * 16 + l16;
        const float invf = exp2f(-0.4152410118609203f * (float)(n_loc & 31));
#pragma unroll
        for (int i = 0; i < 4; i++) {
#pragma unroll
          for (int r = 0; r < 4; r++) {
            const int m_loc = wm + i * 16 + quad * 4 + r;
            float sv, cv;
            sincosf((float)(l0 + m_loc) * invf, &sv, &cv);
            const float x1 = acc[i][jp][r], x2 = acc[i][jp + 2][r];
            sh[m_loc * 136 + n_loc]      = (bf16)((x1 * cv - x2 * sv) * sc);
            sh[m_loc * 136 + n_loc + 32] = (bf16)((x2 * cv + x1 * sv) * sc);
          }
        }
      }
      __syncthreads();
      // rows = l, col segments stay within one head
#pragma unroll
      for (int p = 0; p < 4; p++) {
        const int row = p * 32 + (tid >> 3);
        const int col = (tid & 7) * 16;
        const int n = n0 + col;
        const int hh = (n >> 6) & 15, hd = n & 63;
        bf16* dst = outB + (((size_t)(which * 2 + bb) * 16 + hh) * 2048 + (l0 + row)) * 64 + hd;
        const uint4* src = (const uint4*)&sh[row * 136 + col];
        *(uint4*)dst = src[0];
        *(uint4*)(dst + 8) = src[1];
      }
    }
  } else {  // EP_SILU -> bf16 row-major
#pragma unroll
    for (int i = 0; i < 4; i++) {
#pragma unroll
      for (int j = 0; j < 4; j++) {
        const int n_loc = wn + j * 16 + l16;
#pragma unroll
        for (int r = 0; r < 4; r++) {
          const int m_loc = wm + i * 16 + quad * 4 + r;
          const float val = acc[i][j][r];
          sh[m_loc * 136 + n_loc] = (bf16)(val / (1.0f + __expf(-val)));
        }
      }
    }
    __syncthreads();
#pragma unroll
    for (int p = 0; p < 4; p++) {
      const int row = p * 32 + (tid >> 3);
      const int col = (tid & 7) * 16;
      bf16* dst = outB + (size_t)(m0 + row) * N + n0 + col;
      const uint4* src = (const uint4*)&sh[row * 136 + col];
      *(uint4*)dst = src[0];
      *(uint4*)(dst + 8) = src[1];
    }
  }
}

// ---------------------------------------------------------------- split-K GEMM 128x128, BK=64 (FFN2)
__global__ __launch_bounds__(256)
void gemm_bt_splitk(const bf16* __restrict__ A, const bf16* __restrict__ W,
                    float* __restrict__ P, int M, int N, int Ktot) {
  __shared__ bf16 As[128 * 64];
  __shared__ bf16 Bs[128 * 64];
  const int tid  = threadIdx.x;
  const int wave = tid >> 6;
  const int lane = tid & 63;
  const int quad = lane >> 4;
  const int l16  = lane & 15;

  const int r6 = blockIdx.x & 63;
  const int bn = blockIdx.x >> 6;
  const int bm = r6 >> 1;
  const int split = r6 & 1;
  const int m0 = bm << 7, n0 = bn << 7;
  const int wm = (wave >> 1) << 6;
  const int wn = (wave & 1) << 6;
  const int Kh = Ktot >> 1;
  const int koff = split * Kh;

  const int rl = lane >> 3;
  const int cg = (lane & 7) ^ rl;
  const bf16* gA = A + (size_t)(m0 + wave * 32 + rl) * Ktot + koff + cg * 8;
  const bf16* gB = W + (size_t)(n0 + wave * 32 + rl) * Ktot + koff + cg * 8;

  const int s8 = l16 & 7;
  f32x4 acc[4][4] = {};

  for (int k0 = 0; k0 < Kh; k0 += 64) {
    __syncthreads();
#pragma unroll
    for (int i = 0; i < 4; i++) {
      async_copy16(gA + (size_t)(i * 8) * Ktot, &As[(wave * 32 + i * 8) * 64]);
      async_copy16(gB + (size_t)(i * 8) * Ktot, &Bs[(wave * 32 + i * 8) * 64]);
    }
    gA += 64; gB += 64;
    __syncthreads();
#pragma unroll
    for (int kh = 0; kh < 2; kh++) {
      bf16x8 af[4], bfr[4];
#pragma unroll
      for (int i = 0; i < 4; i++)
        af[i] = *(const bf16x8*)&As[(wm + i * 16 + l16) * 64 + (((kh * 4 + quad) ^ s8) * 8)];
#pragma unroll
      for (int j = 0; j < 4; j++)
        bfr[j] = *(const bf16x8*)&Bs[(wn + j * 16 + l16) * 64 + (((kh * 4 + quad) ^ s8) * 8)];
#pragma unroll
      for (int i = 0; i < 4; i++)
#pragma unroll
        for (int j = 0; j < 4; j++)
          acc[i][j] = __builtin_amdgcn_mfma_f32_16x16x32_bf16(af[i], bfr[j], acc[i][j], 0, 0, 0);
    }
  }

  float* Pd = P + (size_t)split * M * N;
#pragma unroll
  for (int i = 0; i < 4; i++) {
    const int mbase = m0 + wm + i * 16 + quad * 4;
#pragma unroll
    for (int j = 0; j < 4; j++) {
      const int n = n0 + wn + j * 16 + l16;
#pragma unroll
      for (int r = 0; r < 4; r++)
        Pd[(size_t)(mbase + r) * N + n] = acc[i][j][r];
    }
  }
}

// ---------------------------------------------------------------- split-K combine (+resid)
__global__ __launch_bounds__(256)
void splitk_combine(const float* __restrict__ P, const float* __restrict__ resid,
                    float* __restrict__ out, int total4) {
  int i = blockIdx.x * 256 + threadIdx.x;
  if (i < total4) {
    float4 a = ((const float4*)P)[i];
    float4 b = ((const float4*)(P + 4194304))[i];
    float4 r = ((const float4*)resid)[i];
    float4 o;
    o.x = a.x + b.x + r.x; o.y = a.y + b.y + r.y;
    o.z = a.z + b.z + r.z; o.w = a.w + b.w + r.w;
    ((float4*)out)[i] = o;
  }
}

// ---------------------------------------------------------------- GEMM 64x128, BK=64 (out-proj)
__global__ __launch_bounds__(256)
void gemm64_bt(const bf16* __restrict__ A, const bf16* __restrict__ W,
               const float* __restrict__ resid, float* __restrict__ outF,
               int M, int N, int K) {
  __shared__ bf16 As[64 * 64];
  __shared__ bf16 Bs[128 * 64];
  const int tid = threadIdx.x, wave = tid >> 6, lane = tid & 63;
  const int quad = lane >> 4, l16 = lane & 15;
  const int bm = blockIdx.x & 63;
  const int bn = blockIdx.x >> 6;
  const int m0 = bm << 6, n0 = bn << 7;
  const int wm = (wave >> 1) * 32, wn = (wave & 1) * 64;

  const int rl = lane >> 3;
  const int cg = (lane & 7) ^ rl;
  const bf16* gA = A + (size_t)(m0 + wave * 16 + rl) * K + cg * 8;
  const bf16* gB = W + (size_t)(n0 + wave * 32 + rl) * K + cg * 8;

  const int s8 = l16 & 7;
  f32x4 acc[2][4] = {};
  for (int k0 = 0; k0 < K; k0 += 64) {
    __syncthreads();
#pragma unroll
    for (int i = 0; i < 2; i++)
      async_copy16(gA + (size_t)(i * 8) * K, &As[(wave * 16 + i * 8) * 64]);
#pragma unroll
    for (int i = 0; i < 4; i++)
      async_copy16(gB + (size_t)(i * 8) * K, &Bs[(wave * 32 + i * 8) * 64]);
    gA += 64; gB += 64;
    __syncthreads();
#pragma unroll
    for (int kh = 0; kh < 2; kh++) {
      bf16x8 af[2], bfr[4];
#pragma unroll
      for (int i = 0; i < 2; i++)
        af[i] = *(const bf16x8*)&As[(wm + i * 16 + l16) * 64 + (((kh * 4 + quad) ^ s8) * 8)];
#pragma unroll
      for (int j = 0; j < 4; j++)
        bfr[j] = *(const bf16x8*)&Bs[(wn + j * 16 + l16) * 64 + (((kh * 4 + quad) ^ s8) * 8)];
#pragma unroll
      for (int i = 0; i < 2; i++)
#pragma unroll
        for (int j = 0; j < 4; j++)
          acc[i][j] = __builtin_amdgcn_mfma_f32_16x16x32_bf16(af[i], bfr[j], acc[i][j], 0, 0, 0);
    }
  }
#pragma unroll
  for (int i = 0; i < 2; i++) {
    const int mbase = m0 + wm + i * 16 + quad * 4;
#pragma unroll
    for (int j = 0; j < 4; j++) {
      const int n = n0 + wn + j * 16 + l16;
#pragma unroll
      for (int r = 0; r < 4; r++) {
        const int m = mbase + r;
        outF[(size_t)m * N + n] = acc[i][j][r] + resid[(size_t)m * N + n];
      }
    }
  }
}

// ---------------------------------------------------------------- flash attention w/ KV-split
// V^T comes kv-permuted (bits 2,3 swapped per 16-group) so the exp'd S-MFMA
// C-regs, packed pairwise, ARE the PV B-fragment: zero cross-lane exchange.
__global__ __launch_bounds__(256, 4)
void attn_kernel(const bf16* __restrict__ qk, const bf16* __restrict__ vt,
                 bf16* __restrict__ Opart, float* __restrict__ Lpart) {
  const int qt    = blockIdx.x >> 7;
  const int bh    = (blockIdx.x >> 2) & 31;
  const int split = blockIdx.x & 3;
  const bf16* Qp = qk + (size_t)bh * 131072;
  const bf16* Kp = Qp + 4194304;
  const bf16* Vp = vt + (size_t)bh * 131072;

  const int tid = threadIdx.x, wave = tid >> 6, lane = tid & 63;
  const int hl = lane >> 5, l32 = lane & 31;
  const int qw = qt * 128 + wave * 32;

  __shared__ bf16 lds[8192];               // 16 KB: Ks 8K + Vs 8K; epilogue reuses
  bf16* Ks = lds;
  bf16* Vs = lds + 4096;

  bf16x8 qf[4];
#pragma unroll
  for (int dk = 0; dk < 4; dk++)
    qf[dk] = *(const bf16x8*)&Qp[(size_t)(qw + l32) * 64 + dk * 16 + hl * 8];

  f32x16 o0 = {}, o1 = {};
  float sum_acc = 0.0f;

  const int rl = lane >> 3;
  const int cg = (lane & 7) ^ rl;

  const int kvbase = split * 512;
  for (int kv0 = kvbase; kv0 < kvbase + 512; kv0 += 64) {
    __syncthreads();
#pragma unroll
    for (int i = 0; i < 2; i++) {
      const int row = wave * 16 + i * 8;
      async_copy16(Kp + (size_t)(kv0 + row + rl) * 64 + cg * 8, &Ks[row * 64]);
      async_copy16(Vp + (size_t)(row + rl) * 2048 + kv0 + cg * 8, &Vs[row * 64]);
    }
    __syncthreads();

    U4 pf[4];
#pragma unroll
    for (int ks = 0; ks < 2; ks++) {
      f32x16 s = {};
#pragma unroll
      for (int dk = 0; dk < 4; dk++) {
        const bf16x8 kf = *(const bf16x8*)
            &Ks[(ks * 32 + l32) * 64 + ((dk * 2 + hl) ^ (l32 & 7)) * 8];
        s = __builtin_amdgcn_mfma_f32_32x32x16_bf16(kf, qf[dk], s, 0, 0, 0);
      }
#pragma unroll
      for (int c = 0; c < 2; c++)
#pragma unroll
        for (int t = 0; t < 4; t++) {
          const float a = exp2f(s[c * 8 + 2 * t]);
          const float b = exp2f(s[c * 8 + 2 * t + 1]);
          sum_acc += a + b;
          pf[ks * 2 + c].u[t] = pkbf2(a, b);
        }
    }

#pragma unroll
    for (int c16 = 0; c16 < 4; c16++) {
      const bf16x8 vf0 = *(const bf16x8*)&Vs[l32 * 64 + ((c16 * 2 + hl) ^ (l32 & 7)) * 8];
      const bf16x8 vf1 = *(const bf16x8*)&Vs[(32 + l32) * 64 + ((c16 * 2 + hl) ^ (l32 & 7)) * 8];
      o0 = __builtin_amdgcn_mfma_f32_32x32x16_bf16(vf0, pf[c16].v, o0, 0, 0, 0);
      o1 = __builtin_amdgcn_mfma_f32_32x32x16_bf16(vf1, pf[c16].v, o1, 0, 0, 0);
    }
  }

  const float l_i = sum_acc + __shfl_xor(sum_acc, 32, 64);
  Lpart[(size_t)(split * 32 + bh) * 2048 + qt * 128 + wave * 32 + l32] = l_i;

  // epilogue: two passes of 64 q rows through the LDS transpose buffer
  uint* L32 = (uint*)lds;                  // 36 dwords stride per q row
#pragma unroll
  for (int p = 0; p < 2; p++) {
    __syncthreads();
    if ((wave >> 1) == p) {
      const int lrow = (wave & 1) * 32 + l32;
#pragma unroll
      for (int ds = 0; ds < 2; ds++) {
        const f32x16 ov = ds ? o1 : o0;
#pragma unroll
        for (int i = 0; i < 8; i++) {
          const int r = 2 * i;
          const int dd = ds * 32 + (r & 3) + 8 * (r >> 2) + 4 * hl;
          L32[lrow * 36 + (dd >> 1)] = pkbf2(ov[r], ov[r + 1]);
        }
      }
    }
    __syncthreads();
#pragma unroll
    for (int sp = 0; sp < 2; sp++) {
      const int qr = sp * 32 + (tid >> 3), c = tid & 7;
      const uint4 v = *(const uint4*)&L32[qr * 36 + c * 4];
      *(uint4*)&Opart[(((size_t)(split * 32 + bh) * 2048) + qt * 128 + p * 64 + qr) * 64 + c * 8] = v;
    }
  }
}

// ---------------------------------------------------------------- combine attn partials
__global__ __launch_bounds__(256)
void attn_combine(const bf16* __restrict__ Opart, const float* __restrict__ Lpart,
                  bf16* __restrict__ out) {
  const int t = blockIdx.x * 256 + threadIdx.x;
  const int c = t & 7, qq = t >> 3;
  const int bh = qq >> 11, q = qq & 2047;
  const int b = bh >> 4, h = bh & 15;
  float acc[8] = {};
  float lsum = 0.0f;
#pragma unroll
  for (int s = 0; s < 4; s++) {
    const bf16x8 ov = *(const bf16x8*)&Opart[((size_t)(s * 32 + bh) * 2048 + q) * 64 + c * 8];
    lsum += Lpart[(size_t)(s * 32 + bh) * 2048 + q];
#pragma unroll
    for (int i = 0; i < 8; i++) acc[i] += (float)ov[i];
  }
  const float inv = 1.0f / lsum;
  bf16x8 o;
#pragma unroll
  for (int i = 0; i < 8; i++) o[i] = (bf16)(acc[i] * inv);
  *(bf16x8*)&out[((size_t)b * 2048 + q) * 1024 + h * 64 + c * 8] = o;
}

// ---------------------------------------------------------------- launch
extern "C" void kernel_launch(void* const* d_in, const int* in_sizes, int n_in,
                              void* d_out, int out_size, void* d_ws, size_t ws_size,
                              hipStream_t stream) {
  (void)in_sizes; (void)n_in; (void)out_size; (void)ws_size;
  const float* zH    = (const float*)d_in[0];
  const float* zL    = (const float*)d_in[1];
  const float* w_qkv = (const float*)d_in[2];
  const float* w_out = (const float*)d_in[3];
  const float* w_f1  = (const float*)d_in[4];
  const float* w_f2  = (const float*)d_in[5];
  const float* g1    = (const float*)d_in[6];
  const float* g2    = (const float*)d_in[7];
  float* out = (float*)d_out;

  char* ws = (char*)d_ws;
  size_t off = 0;
  auto alloc = [&](size_t bytes) {
    void* p = ws + off;
    off += (bytes + 255) & ~(size_t)255;
    return p;
  };
  bf16*  bqkv  = (bf16*)alloc(3145728ull * 2);
  bf16*  bwout = (bf16*)alloc(1048576ull * 2);
  bf16*  bf1   = (bf16*)alloc(4194304ull * 2);
  bf16*  bf2   = (bf16*)alloc(4194304ull * 2);
  const size_t off_x = off;                      // Ppart aliases x..qkb (dead at FFN2)
  float* x     = (float*)alloc(4194304ull * 4);
  bf16*  hbuf  = (bf16*)alloc(4194304ull * 2);
  bf16*  qkb   = (bf16*)alloc(8388608ull * 2);   // q,k [2][B][H][L][64]
  bf16*  vtb   = (bf16*)alloc(4194304ull * 2);   // V^T [B*H][64][L], kv-permuted
  bf16*  attnb = (bf16*)alloc(4194304ull * 2);
  const size_t offU = off;                       // attn partials alias x2/h2/act
  float* x2    = (float*)alloc(4194304ull * 4);
  bf16*  h2    = (bf16*)alloc(4194304ull * 2);
  bf16*  act   = (bf16*)alloc(16777216ull * 2);
  bf16*  Opart = (bf16*)(ws + offU);
  float* Lpart = (float*)(ws + offU + 16777216ull * 2 + 256);
  float* Ppart = (float*)(ws + off_x);           // 2 x 16 MB fp32 partials (FFN2)

  f2b_all<<<12288, 256, 0, stream>>>(w_qkv, w_out, w_f1, w_f2, bqkv, bwout, bf1, bf2);

  add_rmsnorm_kernel<<<4096, 256, 0, stream>>>(zH, zL, g1, x, hbuf);

  gemm_bt<EP_QKV><<<768, 256, 0, stream>>>(hbuf, bqkv, qkb, vtb, 4096, 3072, 1024);
  attn_kernel<<<2048, 256, 0, stream>>>(qkb, vtb, Opart, Lpart);
  attn_combine<<<2048, 256, 0, stream>>>(Opart, Lpart, attnb);

  gemm64_bt<<<512, 256, 0, stream>>>(attnb, bwout, x, x2, 4096, 1024, 1024);
  add_rmsnorm_kernel<<<4096, 256, 0, stream>>>(x2, nullptr, g2, nullptr, h2);
  gemm_bt<EP_SILU><<<1024, 256, 0, stream>>>(h2, bf1, act, nullptr, 4096, 4096, 1024);
  gemm_bt_splitk<<<512, 256, 0, stream>>>(act, bf2, Ppart, 4096, 1024, 4096);
  splitk_combine<<<4096, 256, 0, stream>>>(Ppart, x2, out, 1048576);
}